// Round 9
// baseline (81.475 us; speedup 1.0000x reference)
//
#include <hip/hip_runtime.h>
#include <hip/hip_bf16.h>

// RBF kernel matrix: out[i][j] = exp(-gamma * max(x2[i] + y2[j] - 2*x.y, 0))
//
// Round 9: r6 structure VERBATIM + NON-TEMPORAL output stores (only change).
// Theory: the 256-MiB output stream thrashes L3 (=256 MiB), evicting the
// 4-MB split inputs that every block re-stages (268 MB logical re-reads) ->
// staging becomes partial HBM reads (+~130 MB ~= +19 us), explaining the
// 56-us main kernel vs the 39-us write floor, and the nulls of r3/r6/r7/r8
// (none stopped the eviction). r4's NT test was confounded by its loop-end
// vmcnt(0) barrier; here stores drain after s_endpgm, off the critical path.
// 3 MFMA passes (hi*hi + lo*hi + hi*lo), drop lo*lo (~1e-21 abs out error).

#define DD 64
#define BM 128
#define BN 128

typedef __attribute__((ext_vector_type(8))) short short8;
typedef __attribute__((ext_vector_type(4))) float f32x4;

#if __has_builtin(__builtin_amdgcn_exp2f)
#define EXP2(x) __builtin_amdgcn_exp2f(x)
#else
#define EXP2(x) exp2f(x)
#endif

__device__ __forceinline__ unsigned short f2bf_rne(float f) {
  unsigned u = __float_as_uint(f);
  unsigned r = u + 0x7FFFu + ((u >> 16) & 1u);
  return (unsigned short)(r >> 16);
}

// ---------------- prep: fp32 norms + bf16 hi/lo pre-split (pre-swizzled) ----
__global__ __launch_bounds__(256)
void prep_split(const float* __restrict__ X, const float* __restrict__ Y,
                unsigned short* __restrict__ XHg, unsigned short* __restrict__ XLg,
                unsigned short* __restrict__ YHg, unsigned short* __restrict__ YLg,
                float* __restrict__ xsq, float* __restrict__ ysq, int n) {
  int t = blockIdx.x * 256 + threadIdx.x;
  int row = t >> 4;       // 16 lanes per row
  int c4 = t & 15;        // float4 index within row
  const float* src;
  unsigned short *hd, *ld;
  float* nd;
  int r;
  if (row < n) { r = row;     src = X + (long)r * DD; hd = XHg; ld = XLg; nd = xsq + r; }
  else         { r = row - n; src = Y + (long)r * DD; hd = YHg; ld = YLg; nd = ysq + r; }
  float4 v = ((const float4*)src)[c4];
  float f[4] = {v.x, v.y, v.z, v.w};
  unsigned short h[4], l[4];
#pragma unroll
  for (int q = 0; q < 4; ++q) {
    h[q] = f2bf_rne(f[q]);
    float hv = __uint_as_float(((unsigned)h[q]) << 16);
    l[q] = f2bf_rne(f[q] - hv);
  }
  int sw = (c4 * 8) ^ ((r & 7) << 4);   // swizzled byte offset within 128-B row
  *(ushort4*)((char*)hd + (long)r * 128 + sw) = make_ushort4(h[0], h[1], h[2], h[3]);
  *(ushort4*)((char*)ld + (long)r * 128 + sw) = make_ushort4(l[0], l[1], l[2], l[3]);
  float s = v.x * v.x + v.y * v.y + v.z * v.z + v.w * v.w;
  s += __shfl_xor(s, 1);
  s += __shfl_xor(s, 2);
  s += __shfl_xor(s, 4);
  s += __shfl_xor(s, 8);
  if (c4 == 0) *nd = s;
}

// ---------------- main: DMA-staged MFMA GEMM, 8 waves of 64x32, NT stores ---
__global__ __launch_bounds__(512, 4)
void rbf_mfma8(const unsigned short* __restrict__ XHg, const unsigned short* __restrict__ XLg,
               const unsigned short* __restrict__ YHg, const unsigned short* __restrict__ YLg,
               const float* __restrict__ gptr,
               const float* __restrict__ xsq, const float* __restrict__ ysq,
               float* __restrict__ Out, int mcols) {
  // 4 tiles of 128 rows x 128 B (swizzled image), 16 KB each = 64 KB.
  __shared__ __align__(128) char lds[65536];

  const int tid = threadIdx.x;
  const int lane = tid & 63;
  const int wid = tid >> 6;        // 0..7
  const long i0 = (long)blockIdx.y * BM;
  const long j0 = (long)blockIdx.x * BN;

  // ---- stage: 4 contiguous 16-KB slices, global_load_lds width 16
  const char* srcs[4] = {(const char*)XHg + i0 * 128, (const char*)XLg + i0 * 128,
                         (const char*)YHg + j0 * 128, (const char*)YLg + j0 * 128};
#pragma unroll
  for (int t4 = 0; t4 < 4; ++t4) {
#pragma unroll
    for (int it = 0; it < 2; ++it) {
      int off = it * 8192 + wid * 1024;           // wave-uniform
      const char* g = srcs[t4] + off + lane * 16; // per-lane global src
      __builtin_amdgcn_global_load_lds(
          (const __attribute__((address_space(1))) void*)g,
          (__attribute__((address_space(3))) void*)(lds + t4 * 16384 + off),
          16, 0, 0);
    }
  }
  __syncthreads();   // compiler drains vmcnt before the barrier

  // ---- MFMA: 3 passes (hi*hi, lo*hi, hi*lo), 2 k-steps of 32 each
  const int wr = wid >> 2;         // 0..1 -> row half (64 rows)
  const int wc = wid & 3;          // 0..3 -> col quarter (32 cols)
  const int lr = lane & 15;
  const int hg = lane >> 4;        // 0..3

  f32x4 acc[4][2];
#pragma unroll
  for (int a = 0; a < 4; ++a)
#pragma unroll
    for (int b = 0; b < 2; ++b) acc[a][b] = (f32x4){0.f, 0.f, 0.f, 0.f};

  const char* At[3] = {lds, lds + 16384, lds};                 // XH, XL, XH
  const char* Bt[3] = {lds + 32768, lds + 32768, lds + 49152}; // YH, YH, YL
#pragma unroll
  for (int p = 0; p < 3; ++p) {
#pragma unroll
    for (int s = 0; s < 2; ++s) {
      const int kbyte = s * 64 + hg * 16;
      short8 af[4], bfv[2];
#pragma unroll
      for (int m2 = 0; m2 < 4; ++m2) {
        int row = wr * 64 + m2 * 16 + lr;
        af[m2] = *(const short8*)(At[p] + row * 128 + (kbyte ^ ((row & 7) << 4)));
      }
#pragma unroll
      for (int n2 = 0; n2 < 2; ++n2) {
        int row = wc * 32 + n2 * 16 + lr;
        bfv[n2] = *(const short8*)(Bt[p] + row * 128 + (kbyte ^ ((row & 7) << 4)));
      }
      // Swapped operands: reg dim = Y rows (output cols), lane&15 = X rows.
#pragma unroll
      for (int m2 = 0; m2 < 4; ++m2)
#pragma unroll
        for (int n2 = 0; n2 < 2; ++n2)
          acc[m2][n2] = __builtin_amdgcn_mfma_f32_16x16x32_bf16(bfv[n2], af[m2], acc[m2][n2], 0, 0, 0);
    }
  }

  // ---- epilogue: out = 2^( min( c*x2 + c*y2 + 2|c|*xy, 0 ) ), c = -g*log2e
  // NT stores: bypass cache allocation so the write stream doesn't evict the
  // L3-resident split inputs. No trailing barrier -> drain is off-path.
  const float g = *gptr;
  const float cf = -g * 1.4426950408889634f;
  const float nc2 = -2.0f * cf;
  float cxr[4];
#pragma unroll
  for (int m2 = 0; m2 < 4; ++m2) cxr[m2] = cf * xsq[i0 + wr * 64 + m2 * 16 + lr];
  float4 cyv[2];
#pragma unroll
  for (int n2 = 0; n2 < 2; ++n2) {
    float4 yq = *(const float4*)&ysq[j0 + wc * 32 + n2 * 16 + hg * 4];
    cyv[n2] = make_float4(cf * yq.x, cf * yq.y, cf * yq.z, cf * yq.w);
  }
#pragma unroll
  for (int m2 = 0; m2 < 4; ++m2) {
    long row = i0 + wr * 64 + m2 * 16 + lr;
    float* op = Out + row * (long)mcols + j0 + wc * 32 + hg * 4;
#pragma unroll
    for (int n2 = 0; n2 < 2; ++n2) {
      float cy[4] = {cyv[n2].x, cyv[n2].y, cyv[n2].z, cyv[n2].w};
      f32x4 o;
#pragma unroll
      for (int j = 0; j < 4; ++j)
        o[j] = EXP2(fminf(fmaf(nc2, acc[m2][n2][j], cxr[m2] + cy[j]), 0.f));
      __builtin_nontemporal_store(o, (f32x4*)(op + n2 * 16));
    }
  }
}

// ---------------- fallback (proven round-2 path) ---------------------------
__global__ __launch_bounds__(256)
void prep_sq(const float* __restrict__ X, const float* __restrict__ Y,
             float* __restrict__ xsq, float* __restrict__ ysq, int n) {
  int t = blockIdx.x * 256 + threadIdx.x;
  int row = t >> 4;
  int c = t & 15;
  const float* src;
  float* dst;
  if (row < n) { src = X + (long)row * DD; dst = xsq + row; }
  else         { src = Y + (long)(row - n) * DD; dst = ysq + (row - n); }
  float4 v = ((const float4*)src)[c];
  float s = v.x * v.x + v.y * v.y + v.z * v.z + v.w * v.w;
  s += __shfl_xor(s, 1);
  s += __shfl_xor(s, 2);
  s += __shfl_xor(s, 4);
  s += __shfl_xor(s, 8);
  if (c == 0) *dst = s;
}

__global__ __launch_bounds__(256, 2)
void rbf_mfma_fb(const float* __restrict__ X, const float* __restrict__ Y,
                 const float* __restrict__ gptr,
                 const float* __restrict__ xsq, const float* __restrict__ ysq,
                 float* __restrict__ Out, int mcols) {
  __shared__ unsigned short XH[128 * DD], XL[128 * DD];
  __shared__ unsigned short YH[128 * DD], YL[128 * DD];
  const int tid = threadIdx.x;
  const long i0 = (long)blockIdx.y * 128;
  const long j0 = (long)blockIdx.x * 128;
#pragma unroll
  for (int it = 0; it < 16; ++it) {
    int e = it * 256 + tid;
    int half = e >> 11;
    int idx = e & 2047;
    int row = idx >> 4;
    int c4 = idx & 15;
    const float* src = half ? (Y + (j0 + row) * DD) : (X + (i0 + row) * DD);
    float4 v = ((const float4*)src)[c4];
    float f[4] = {v.x, v.y, v.z, v.w};
    unsigned short h[4], l[4];
#pragma unroll
    for (int q = 0; q < 4; ++q) {
      h[q] = f2bf_rne(f[q]);
      float hv = __uint_as_float(((unsigned)h[q]) << 16);
      l[q] = f2bf_rne(f[q] - hv);
    }
    int sw = (c4 * 8) ^ ((row & 7) << 4);
    unsigned short* Ht = half ? YH : XH;
    unsigned short* Lt = half ? YL : XL;
    *(ushort4*)((char*)Ht + row * 128 + sw) = make_ushort4(h[0], h[1], h[2], h[3]);
    *(ushort4*)((char*)Lt + row * 128 + sw) = make_ushort4(l[0], l[1], l[2], l[3]);
  }
  __syncthreads();
  const int lane = tid & 63;
  const int wid = tid >> 6;
  const int wr = wid >> 1, wc = wid & 1;
  const int lr = lane & 15;
  const int hg = lane >> 4;
  f32x4 acc[4][4];
#pragma unroll
  for (int a = 0; a < 4; ++a)
#pragma unroll
    for (int c = 0; c < 4; ++c) acc[a][c] = (f32x4){0.f, 0.f, 0.f, 0.f};
  const unsigned short* At[3] = {XH, XL, XH};
  const unsigned short* Bt[3] = {YH, YH, YL};
#pragma unroll
  for (int p = 0; p < 3; ++p) {
#pragma unroll
    for (int s = 0; s < 2; ++s) {
      const int kbyte = s * 64 + hg * 16;
      short8 af[4], bfv[4];
#pragma unroll
      for (int m2 = 0; m2 < 4; ++m2) {
        int row = wr * 64 + m2 * 16 + lr;
        af[m2] = *(const short8*)((const char*)At[p] + row * 128 + (kbyte ^ ((row & 7) << 4)));
      }
#pragma unroll
      for (int n2 = 0; n2 < 4; ++n2) {
        int row = wc * 64 + n2 * 16 + lr;
        bfv[n2] = *(const short8*)((const char*)Bt[p] + row * 128 + (kbyte ^ ((row & 7) << 4)));
      }
#pragma unroll
      for (int m2 = 0; m2 < 4; ++m2)
#pragma unroll
        for (int n2 = 0; n2 < 4; ++n2)
          acc[m2][n2] = __builtin_amdgcn_mfma_f32_16x16x32_bf16(af[m2], bfv[n2], acc[m2][n2], 0, 0, 0);
    }
  }
  const float g = *gptr;
  float yv[4];
#pragma unroll
  for (int n2 = 0; n2 < 4; ++n2) yv[n2] = ysq[j0 + wc * 64 + n2 * 16 + lr];
#pragma unroll
  for (int m2 = 0; m2 < 4; ++m2) {
#pragma unroll
    for (int j = 0; j < 4; ++j) {
      long row = i0 + wr * 64 + m2 * 16 + hg * 4 + j;
      float xr = xsq[row];
      float* op = Out + row * (long)mcols + j0 + wc * 64 + lr;
#pragma unroll
      for (int n2 = 0; n2 < 4; ++n2) {
        float d = fmaxf(xr + yv[n2] - 2.0f * acc[m2][n2][j], 0.f);
        op[n2 * 16] = __expf(-g * d);
      }
    }
  }
}

extern "C" void kernel_launch(void* const* d_in, const int* in_sizes, int n_in,
                              void* d_out, int out_size, void* d_ws, size_t ws_size,
                              hipStream_t stream) {
  const float* x = (const float*)d_in[0];
  const float* y = (const float*)d_in[1];
  const float* g = (const float*)d_in[2];
  float* out = (float*)d_out;

  const int n = in_sizes[0] / DD;   // 8192
  const int m = in_sizes[1] / DD;   // 8192

  const size_t split_bytes = (size_t)(n + m) * DD * 2 * sizeof(unsigned short);
  const size_t needed = split_bytes + (size_t)(n + m) * sizeof(float);

  dim3 grid(m / BN, n / BM);        // 64 x 64 = 4096 blocks

  if (ws_size >= needed && (n % BM) == 0 && (m % BN) == 0) {
    unsigned short* XHg = (unsigned short*)d_ws;
    unsigned short* XLg = XHg + (size_t)n * DD;
    unsigned short* YHg = XLg + (size_t)n * DD;
    unsigned short* YLg = YHg + (size_t)m * DD;
    float* xsq = (float*)(YLg + (size_t)m * DD);
    float* ysq = xsq + n;
    prep_split<<<(n + m) / 16, 256, 0, stream>>>(x, y, XHg, XLg, YHg, YLg, xsq, ysq, n);
    rbf_mfma8<<<grid, 512, 0, stream>>>(XHg, XLg, YHg, YLg, g, xsq, ysq, out, m);
  } else {
    float* xsq = (float*)d_ws;
    float* ysq = xsq + n;
    prep_sq<<<(n + m) / 16, 256, 0, stream>>>(x, y, xsq, ysq, n);
    dim3 grid2(m / 128, n / 128);
    rbf_mfma_fb<<<grid2, 256, 0, stream>>>(x, y, g, xsq, ysq, out, m);
  }
}

// Round 10
// 65.695 us; speedup vs baseline: 1.2402x; 1.2402x over previous
//
#include <hip/hip_runtime.h>
#include <hip/hip_bf16.h>

// RBF kernel matrix: out[i][j] = exp(-gamma * max(x2[i] + y2[j] - 2*x.y, 0))
//
// Round 10: raise block-level phase overlap. Evidence: r2/r3/r6/r7/r8 all
// ~61us = 68% of fill-calibrated write BW, all at 2 blocks/CU; barrier
// phase-locks waves so each block alternates {no-store: stage+MFMA, f~0.55}
// and {store burst}. Store-pipe busy ~ 1-f^k; k=2 -> 70% (matches!).
// Fix: 64x64 tiles, 32 KB LDS -> k=5 blocks/CU (160KB exactly), 20 waves/CU
// -> 1-0.55^5 ~ 95%. Same structure as r6 otherwise: DMA staging, 3-pass
// hi/lo MFMA (drop lo*lo, ~1e-21 abs err), fused exp2 epilogue, NORMAL
// float4 stores (NT condemned twice: r4, r9).

#define DD 64
#define BM 64
#define BN 64

typedef __attribute__((ext_vector_type(8))) short short8;
typedef __attribute__((ext_vector_type(4))) float f32x4;

#if __has_builtin(__builtin_amdgcn_exp2f)
#define EXP2(x) __builtin_amdgcn_exp2f(x)
#else
#define EXP2(x) exp2f(x)
#endif

__device__ __forceinline__ unsigned short f2bf_rne(float f) {
  unsigned u = __float_as_uint(f);
  unsigned r = u + 0x7FFFu + ((u >> 16) & 1u);
  return (unsigned short)(r >> 16);
}

// ---------------- prep: fp32 norms + bf16 hi/lo pre-split (pre-swizzled) ----
__global__ __launch_bounds__(256)
void prep_split(const float* __restrict__ X, const float* __restrict__ Y,
                unsigned short* __restrict__ XHg, unsigned short* __restrict__ XLg,
                unsigned short* __restrict__ YHg, unsigned short* __restrict__ YLg,
                float* __restrict__ xsq, float* __restrict__ ysq, int n) {
  int t = blockIdx.x * 256 + threadIdx.x;
  int row = t >> 4;       // 16 lanes per row
  int c4 = t & 15;        // float4 index within row
  const float* src;
  unsigned short *hd, *ld;
  float* nd;
  int r;
  if (row < n) { r = row;     src = X + (long)r * DD; hd = XHg; ld = XLg; nd = xsq + r; }
  else         { r = row - n; src = Y + (long)r * DD; hd = YHg; ld = YLg; nd = ysq + r; }
  float4 v = ((const float4*)src)[c4];
  float f[4] = {v.x, v.y, v.z, v.w};
  unsigned short h[4], l[4];
#pragma unroll
  for (int q = 0; q < 4; ++q) {
    h[q] = f2bf_rne(f[q]);
    float hv = __uint_as_float(((unsigned)h[q]) << 16);
    l[q] = f2bf_rne(f[q] - hv);
  }
  int sw = (c4 * 8) ^ ((r & 7) << 4);   // swizzled byte offset within 128-B row
  *(ushort4*)((char*)hd + (long)r * 128 + sw) = make_ushort4(h[0], h[1], h[2], h[3]);
  *(ushort4*)((char*)ld + (long)r * 128 + sw) = make_ushort4(l[0], l[1], l[2], l[3]);
  float s = v.x * v.x + v.y * v.y + v.z * v.z + v.w * v.w;
  s += __shfl_xor(s, 1);
  s += __shfl_xor(s, 2);
  s += __shfl_xor(s, 4);
  s += __shfl_xor(s, 8);
  if (c4 == 0) *nd = s;
}

// ---------------- main: 64x64 tile, 4 waves, 32 KB LDS, 5 blocks/CU --------
__global__ __launch_bounds__(256, 5)
void rbf_mfma64(const unsigned short* __restrict__ XHg, const unsigned short* __restrict__ XLg,
                const unsigned short* __restrict__ YHg, const unsigned short* __restrict__ YLg,
                const float* __restrict__ gptr,
                const float* __restrict__ xsq, const float* __restrict__ ysq,
                float* __restrict__ Out, int mcols) {
  // 4 images of 64 rows x 128 B (swizzled), 8 KB each = 32 KB total.
  __shared__ __align__(128) char lds[32768];

  const int tid = threadIdx.x;
  const int lane = tid & 63;
  const int wid = tid >> 6;        // 0..3
  const long i0 = (long)blockIdx.y * BM;
  const long j0 = (long)blockIdx.x * BN;

  // ---- stage: 4 contiguous 8-KB slices, global_load_lds width 16
  const char* srcs[4] = {(const char*)XHg + i0 * 128, (const char*)XLg + i0 * 128,
                         (const char*)YHg + j0 * 128, (const char*)YLg + j0 * 128};
#pragma unroll
  for (int t4 = 0; t4 < 4; ++t4) {
#pragma unroll
    for (int it = 0; it < 2; ++it) {
      int off = it * 4096 + wid * 1024;           // wave-uniform
      const char* g = srcs[t4] + off + lane * 16; // per-lane global src
      __builtin_amdgcn_global_load_lds(
          (const __attribute__((address_space(1))) void*)g,
          (__attribute__((address_space(3))) void*)(lds + t4 * 8192 + off),
          16, 0, 0);
    }
  }
  __syncthreads();   // compiler drains vmcnt before the barrier

  // ---- MFMA: 3 passes (hi*hi, lo*hi, hi*lo), 2 k-steps of 32 each
  const int wr = wid >> 1;         // 0..1 -> 32-row half
  const int wc = wid & 1;          // 0..1 -> 32-col half
  const int lr = lane & 15;
  const int hg = lane >> 4;        // 0..3

  f32x4 acc[2][2];
#pragma unroll
  for (int a = 0; a < 2; ++a)
#pragma unroll
    for (int b = 0; b < 2; ++b) acc[a][b] = (f32x4){0.f, 0.f, 0.f, 0.f};

  const char* At[3] = {lds, lds + 8192, lds};                  // XH, XL, XH
  const char* Bt[3] = {lds + 16384, lds + 16384, lds + 24576}; // YH, YH, YL
#pragma unroll
  for (int p = 0; p < 3; ++p) {
#pragma unroll
    for (int s = 0; s < 2; ++s) {
      const int kbyte = s * 64 + hg * 16;
      short8 af[2], bfv[2];
#pragma unroll
      for (int m2 = 0; m2 < 2; ++m2) {
        int row = wr * 32 + m2 * 16 + lr;
        af[m2] = *(const short8*)(At[p] + row * 128 + (kbyte ^ ((row & 7) << 4)));
      }
#pragma unroll
      for (int n2 = 0; n2 < 2; ++n2) {
        int row = wc * 32 + n2 * 16 + lr;
        bfv[n2] = *(const short8*)(Bt[p] + row * 128 + (kbyte ^ ((row & 7) << 4)));
      }
      // Swapped operands: reg dim = Y rows (output cols), lane&15 = X rows.
#pragma unroll
      for (int m2 = 0; m2 < 2; ++m2)
#pragma unroll
        for (int n2 = 0; n2 < 2; ++n2)
          acc[m2][n2] = __builtin_amdgcn_mfma_f32_16x16x32_bf16(bfv[n2], af[m2], acc[m2][n2], 0, 0, 0);
    }
  }

  // ---- epilogue: out = 2^( min( c*x2 + c*y2 + 2|c|*xy, 0 ) ), c = -g*log2e
  const float g = *gptr;
  const float cf = -g * 1.4426950408889634f;
  const float nc2 = -2.0f * cf;
  float cxr[2];
#pragma unroll
  for (int m2 = 0; m2 < 2; ++m2) cxr[m2] = cf * xsq[i0 + wr * 32 + m2 * 16 + lr];
  float4 cyv[2];
#pragma unroll
  for (int n2 = 0; n2 < 2; ++n2) {
    float4 yq = *(const float4*)&ysq[j0 + wc * 32 + n2 * 16 + hg * 4];
    cyv[n2] = make_float4(cf * yq.x, cf * yq.y, cf * yq.z, cf * yq.w);
  }
#pragma unroll
  for (int m2 = 0; m2 < 2; ++m2) {
    long row = i0 + wr * 32 + m2 * 16 + lr;
    float* op = Out + row * (long)mcols + j0 + wc * 32 + hg * 4;
#pragma unroll
    for (int n2 = 0; n2 < 2; ++n2) {
      float cy[4] = {cyv[n2].x, cyv[n2].y, cyv[n2].z, cyv[n2].w};
      float o[4];
#pragma unroll
      for (int j = 0; j < 4; ++j)
        o[j] = EXP2(fminf(fmaf(nc2, acc[m2][n2][j], cxr[m2] + cy[j]), 0.f));
      *(float4*)(op + n2 * 16) = *(float4*)o;
    }
  }
}

// ---------------- fallback (proven round-2 path) ---------------------------
__global__ __launch_bounds__(256)
void prep_sq(const float* __restrict__ X, const float* __restrict__ Y,
             float* __restrict__ xsq, float* __restrict__ ysq, int n) {
  int t = blockIdx.x * 256 + threadIdx.x;
  int row = t >> 4;
  int c = t & 15;
  const float* src;
  float* dst;
  if (row < n) { src = X + (long)row * DD; dst = xsq + row; }
  else         { src = Y + (long)(row - n) * DD; dst = ysq + (row - n); }
  float4 v = ((const float4*)src)[c];
  float s = v.x * v.x + v.y * v.y + v.z * v.z + v.w * v.w;
  s += __shfl_xor(s, 1);
  s += __shfl_xor(s, 2);
  s += __shfl_xor(s, 4);
  s += __shfl_xor(s, 8);
  if (c == 0) *dst = s;
}

__global__ __launch_bounds__(256, 2)
void rbf_mfma_fb(const float* __restrict__ X, const float* __restrict__ Y,
                 const float* __restrict__ gptr,
                 const float* __restrict__ xsq, const float* __restrict__ ysq,
                 float* __restrict__ Out, int mcols) {
  __shared__ unsigned short XH[128 * DD], XL[128 * DD];
  __shared__ unsigned short YH[128 * DD], YL[128 * DD];
  const int tid = threadIdx.x;
  const long i0 = (long)blockIdx.y * 128;
  const long j0 = (long)blockIdx.x * 128;
#pragma unroll
  for (int it = 0; it < 16; ++it) {
    int e = it * 256 + tid;
    int half = e >> 11;
    int idx = e & 2047;
    int row = idx >> 4;
    int c4 = idx & 15;
    const float* src = half ? (Y + (j0 + row) * DD) : (X + (i0 + row) * DD);
    float4 v = ((const float4*)src)[c4];
    float f[4] = {v.x, v.y, v.z, v.w};
    unsigned short h[4], l[4];
#pragma unroll
    for (int q = 0; q < 4; ++q) {
      h[q] = f2bf_rne(f[q]);
      float hv = __uint_as_float(((unsigned)h[q]) << 16);
      l[q] = f2bf_rne(f[q] - hv);
    }
    int sw = (c4 * 8) ^ ((row & 7) << 4);
    unsigned short* Ht = half ? YH : XH;
    unsigned short* Lt = half ? YL : XL;
    *(ushort4*)((char*)Ht + row * 128 + sw) = make_ushort4(h[0], h[1], h[2], h[3]);
    *(ushort4*)((char*)Lt + row * 128 + sw) = make_ushort4(l[0], l[1], l[2], l[3]);
  }
  __syncthreads();
  const int lane = tid & 63;
  const int wid = tid >> 6;
  const int wr = wid >> 1, wc = wid & 1;
  const int lr = lane & 15;
  const int hg = lane >> 4;
  f32x4 acc[4][4];
#pragma unroll
  for (int a = 0; a < 4; ++a)
#pragma unroll
    for (int c = 0; c < 4; ++c) acc[a][c] = (f32x4){0.f, 0.f, 0.f, 0.f};
  const unsigned short* At[3] = {XH, XL, XH};
  const unsigned short* Bt[3] = {YH, YH, YL};
#pragma unroll
  for (int p = 0; p < 3; ++p) {
#pragma unroll
    for (int s = 0; s < 2; ++s) {
      const int kbyte = s * 64 + hg * 16;
      short8 af[4], bfv[4];
#pragma unroll
      for (int m2 = 0; m2 < 4; ++m2) {
        int row = wr * 64 + m2 * 16 + lr;
        af[m2] = *(const short8*)((const char*)At[p] + row * 128 + (kbyte ^ ((row & 7) << 4)));
      }
#pragma unroll
      for (int n2 = 0; n2 < 4; ++n2) {
        int row = wc * 64 + n2 * 16 + lr;
        bfv[n2] = *(const short8*)((const char*)Bt[p] + row * 128 + (kbyte ^ ((row & 7) << 4)));
      }
#pragma unroll
      for (int m2 = 0; m2 < 4; ++m2)
#pragma unroll
        for (int n2 = 0; n2 < 4; ++n2)
          acc[m2][n2] = __builtin_amdgcn_mfma_f32_16x16x32_bf16(af[m2], bfv[n2], acc[m2][n2], 0, 0, 0);
    }
  }
  const float g = *gptr;
  float yv[4];
#pragma unroll
  for (int n2 = 0; n2 < 4; ++n2) yv[n2] = ysq[j0 + wc * 64 + n2 * 16 + lr];
#pragma unroll
  for (int m2 = 0; m2 < 4; ++m2) {
#pragma unroll
    for (int j = 0; j < 4; ++j) {
      long row = i0 + wr * 64 + m2 * 16 + hg * 4 + j;
      float xr = xsq[row];
      float* op = Out + row * (long)mcols + j0 + wc * 64 + lr;
#pragma unroll
      for (int n2 = 0; n2 < 4; ++n2) {
        float d = fmaxf(xr + yv[n2] - 2.0f * acc[m2][n2][j], 0.f);
        op[n2 * 16] = __expf(-g * d);
      }
    }
  }
}

extern "C" void kernel_launch(void* const* d_in, const int* in_sizes, int n_in,
                              void* d_out, int out_size, void* d_ws, size_t ws_size,
                              hipStream_t stream) {
  const float* x = (const float*)d_in[0];
  const float* y = (const float*)d_in[1];
  const float* g = (const float*)d_in[2];
  float* out = (float*)d_out;

  const int n = in_sizes[0] / DD;   // 8192
  const int m = in_sizes[1] / DD;   // 8192

  const size_t split_bytes = (size_t)(n + m) * DD * 2 * sizeof(unsigned short);
  const size_t needed = split_bytes + (size_t)(n + m) * sizeof(float);

  if (ws_size >= needed && (n % BM) == 0 && (m % BN) == 0) {
    unsigned short* XHg = (unsigned short*)d_ws;
    unsigned short* XLg = XHg + (size_t)n * DD;
    unsigned short* YHg = XLg + (size_t)n * DD;
    unsigned short* YLg = YHg + (size_t)m * DD;
    float* xsq = (float*)(YLg + (size_t)m * DD);
    float* ysq = xsq + n;
    prep_split<<<(n + m) / 16, 256, 0, stream>>>(x, y, XHg, XLg, YHg, YLg, xsq, ysq, n);
    dim3 grid(m / BN, n / BM);      // 128 x 128 = 16384 blocks
    rbf_mfma64<<<grid, 256, 0, stream>>>(XHg, XLg, YHg, YLg, g, xsq, ysq, out, m);
  } else {
    float* xsq = (float*)d_ws;
    float* ysq = xsq + n;
    prep_sq<<<(n + m) / 16, 256, 0, stream>>>(x, y, xsq, ysq, n);
    dim3 grid2(m / 128, n / 128);
    rbf_mfma_fb<<<grid2, 256, 0, stream>>>(x, y, g, xsq, ysq, out, m);
  }
}

// Round 11
// 58.326 us; speedup vs baseline: 1.3969x; 1.1264x over previous
//
#include <hip/hip_runtime.h>
#include <hip/hip_bf16.h>

// RBF kernel matrix: out[i][j] = exp(-gamma * max(x2[i] + y2[j] - 2*x.y, 0))
//
// Round 11: r3 base (best, 60.9us) with STRIP-INTERLEAVED epilogue.
// Diagnosis: all resident blocks run in deterministic lockstep (start
// together, identical work) -> synchronized {stage+MFMA: HBM-idle} and
// {store-burst} phases -> ~33% HBM write-pipe idle = 4.7/6.9 TB/s (68%),
// invariant to staging/occupancy/tile/XCD-map/blocks-per-CU (r3..r10).
// Fix: n2-outer loop -- per 16-col strip: load Y frags, 24 MFMAs, exp,
// 4 float4 stores. Stores spread across the wave lifetime (25/50/75/100%),
// no barrier after them, no dependents -> drain under next strip's MFMAs.
// 3 MFMA passes (hi*hi + loY*hiX + hiY*loX), drop lo*lo (~1e-21 abs err).

#define DD 64
#define BM 128
#define BN 128

typedef __attribute__((ext_vector_type(8))) short short8;
typedef __attribute__((ext_vector_type(4))) float f32x4;

#if __has_builtin(__builtin_amdgcn_exp2f)
#define EXP2(x) __builtin_amdgcn_exp2f(x)
#else
#define EXP2(x) exp2f(x)
#endif

__device__ __forceinline__ unsigned short f2bf_rne(float f) {
  unsigned u = __float_as_uint(f);
  unsigned r = u + 0x7FFFu + ((u >> 16) & 1u);
  return (unsigned short)(r >> 16);
}

// ---------------- prep: fp32 norms + bf16 hi/lo pre-split (pre-swizzled) ----
__global__ __launch_bounds__(256)
void prep_split(const float* __restrict__ X, const float* __restrict__ Y,
                unsigned short* __restrict__ XHg, unsigned short* __restrict__ XLg,
                unsigned short* __restrict__ YHg, unsigned short* __restrict__ YLg,
                float* __restrict__ xsq, float* __restrict__ ysq, int n) {
  int t = blockIdx.x * 256 + threadIdx.x;
  int row = t >> 4;       // 16 lanes per row
  int c4 = t & 15;        // float4 index within row
  const float* src;
  unsigned short *hd, *ld;
  float* nd;
  int r;
  if (row < n) { r = row;     src = X + (long)r * DD; hd = XHg; ld = XLg; nd = xsq + r; }
  else         { r = row - n; src = Y + (long)r * DD; hd = YHg; ld = YLg; nd = ysq + r; }
  float4 v = ((const float4*)src)[c4];
  float f[4] = {v.x, v.y, v.z, v.w};
  unsigned short h[4], l[4];
#pragma unroll
  for (int q = 0; q < 4; ++q) {
    h[q] = f2bf_rne(f[q]);
    float hv = __uint_as_float(((unsigned)h[q]) << 16);
    l[q] = f2bf_rne(f[q] - hv);
  }
  int sw = (c4 * 8) ^ ((r & 7) << 4);   // swizzled byte offset within 128-B row
  *(ushort4*)((char*)hd + (long)r * 128 + sw) = make_ushort4(h[0], h[1], h[2], h[3]);
  *(ushort4*)((char*)ld + (long)r * 128 + sw) = make_ushort4(l[0], l[1], l[2], l[3]);
  float s = v.x * v.x + v.y * v.y + v.z * v.z + v.w * v.w;
  s += __shfl_xor(s, 1);
  s += __shfl_xor(s, 2);
  s += __shfl_xor(s, 4);
  s += __shfl_xor(s, 8);
  if (c4 == 0) *nd = s;
}

// ---------------- main: DMA-staged MFMA GEMM, strip-interleaved stores ------
__global__ __launch_bounds__(256, 2)
void rbf_strip(const unsigned short* __restrict__ XHg, const unsigned short* __restrict__ XLg,
               const unsigned short* __restrict__ YHg, const unsigned short* __restrict__ YLg,
               const float* __restrict__ gptr,
               const float* __restrict__ xsq, const float* __restrict__ ysq,
               float* __restrict__ Out, int mcols) {
  // 4 tiles of 128 rows x 128 B (swizzled image), 16 KB each = 64 KB.
  __shared__ __align__(128) char lds[65536];

  const int tid = threadIdx.x;
  const int lane = tid & 63;
  const int wid = tid >> 6;        // 0..3
  const long i0 = (long)blockIdx.y * BM;
  const long j0 = (long)blockIdx.x * BN;

  // ---- stage: 4 contiguous 16-KB slices, global_load_lds width 16
  const char* srcs[4] = {(const char*)XHg + i0 * 128, (const char*)XLg + i0 * 128,
                         (const char*)YHg + j0 * 128, (const char*)YLg + j0 * 128};
#pragma unroll
  for (int t4 = 0; t4 < 4; ++t4) {
#pragma unroll
    for (int it = 0; it < 4; ++it) {
      int off = it * 4096 + wid * 1024;           // wave-uniform
      const char* g = srcs[t4] + off + lane * 16; // per-lane global src
      __builtin_amdgcn_global_load_lds(
          (const __attribute__((address_space(1))) void*)g,
          (__attribute__((address_space(3))) void*)(lds + t4 * 16384 + off),
          16, 0, 0);
    }
  }
  __syncthreads();   // compiler drains vmcnt before the barrier

  const int wr = wid >> 1, wc = wid & 1;
  const int lr = lane & 15;
  const int hg = lane >> 4;        // 0..3

  // ---- hoist A-fragments (XH, XL), reused by every strip
  short8 afh[2][4], afl[2][4];     // [s][m2]
#pragma unroll
  for (int s = 0; s < 2; ++s)
#pragma unroll
    for (int m2 = 0; m2 < 4; ++m2) {
      int row = wr * 64 + m2 * 16 + lr;
      int off = (s * 64 + hg * 16) ^ ((row & 7) << 4);
      afh[s][m2] = *(const short8*)(lds + row * 128 + off);
      afl[s][m2] = *(const short8*)(lds + 16384 + row * 128 + off);
    }

  const float g = *gptr;
  const float cf = -g * 1.4426950408889634f;   // -gamma*log2(e)
  const float nc2 = -2.0f * cf;
  float cxr[4];
#pragma unroll
  for (int m2 = 0; m2 < 4; ++m2) cxr[m2] = cf * xsq[i0 + wr * 64 + m2 * 16 + lr];

  // ---- per 16-col strip: Y frags -> 24 MFMAs -> exp -> 4 stores (no burst)
#pragma unroll
  for (int n2 = 0; n2 < 4; ++n2) {
    short8 bfh[2], bfl[2];
#pragma unroll
    for (int s = 0; s < 2; ++s) {
      int row = wc * 64 + n2 * 16 + lr;
      int off = (s * 64 + hg * 16) ^ ((row & 7) << 4);
      bfh[s] = *(const short8*)(lds + 32768 + row * 128 + off);
      bfl[s] = *(const short8*)(lds + 49152 + row * 128 + off);
    }

    f32x4 acc[4];
#pragma unroll
    for (int m2 = 0; m2 < 4; ++m2) acc[m2] = (f32x4){0.f, 0.f, 0.f, 0.f};

#pragma unroll
    for (int s = 0; s < 2; ++s) {
#pragma unroll
      for (int m2 = 0; m2 < 4; ++m2)
        acc[m2] = __builtin_amdgcn_mfma_f32_16x16x32_bf16(bfh[s], afh[s][m2], acc[m2], 0, 0, 0);
#pragma unroll
      for (int m2 = 0; m2 < 4; ++m2)
        acc[m2] = __builtin_amdgcn_mfma_f32_16x16x32_bf16(bfh[s], afl[s][m2], acc[m2], 0, 0, 0);
#pragma unroll
      for (int m2 = 0; m2 < 4; ++m2)
        acc[m2] = __builtin_amdgcn_mfma_f32_16x16x32_bf16(bfl[s], afh[s][m2], acc[m2], 0, 0, 0);
    }

    // strip epilogue + stores (drain under next strip's MFMAs)
    float4 yq = *(const float4*)&ysq[j0 + wc * 64 + n2 * 16 + hg * 4];
    float cy[4] = {cf * yq.x, cf * yq.y, cf * yq.z, cf * yq.w};
#pragma unroll
    for (int m2 = 0; m2 < 4; ++m2) {
      long row = i0 + wr * 64 + m2 * 16 + lr;
      float* op = Out + row * (long)mcols + j0 + wc * 64 + hg * 4;
      float o[4];
#pragma unroll
      for (int j = 0; j < 4; ++j)
        o[j] = EXP2(fminf(fmaf(nc2, acc[m2][j], cxr[m2] + cy[j]), 0.f));
      *(float4*)(op + n2 * 16) = *(float4*)o;
    }
  }
}

// ---------------- fallback (proven round-2 path) ---------------------------
__global__ __launch_bounds__(256)
void prep_sq(const float* __restrict__ X, const float* __restrict__ Y,
             float* __restrict__ xsq, float* __restrict__ ysq, int n) {
  int t = blockIdx.x * 256 + threadIdx.x;
  int row = t >> 4;
  int c = t & 15;
  const float* src;
  float* dst;
  if (row < n) { src = X + (long)row * DD; dst = xsq + row; }
  else         { src = Y + (long)(row - n) * DD; dst = ysq + (row - n); }
  float4 v = ((const float4*)src)[c];
  float s = v.x * v.x + v.y * v.y + v.z * v.z + v.w * v.w;
  s += __shfl_xor(s, 1);
  s += __shfl_xor(s, 2);
  s += __shfl_xor(s, 4);
  s += __shfl_xor(s, 8);
  if (c == 0) *dst = s;
}

__global__ __launch_bounds__(256, 2)
void rbf_mfma_fb(const float* __restrict__ X, const float* __restrict__ Y,
                 const float* __restrict__ gptr,
                 const float* __restrict__ xsq, const float* __restrict__ ysq,
                 float* __restrict__ Out, int mcols) {
  __shared__ unsigned short XH[128 * DD], XL[128 * DD];
  __shared__ unsigned short YH[128 * DD], YL[128 * DD];
  const int tid = threadIdx.x;
  const long i0 = (long)blockIdx.y * 128;
  const long j0 = (long)blockIdx.x * 128;
#pragma unroll
  for (int it = 0; it < 16; ++it) {
    int e = it * 256 + tid;
    int half = e >> 11;
    int idx = e & 2047;
    int row = idx >> 4;
    int c4 = idx & 15;
    const float* src = half ? (Y + (j0 + row) * DD) : (X + (i0 + row) * DD);
    float4 v = ((const float4*)src)[c4];
    float f[4] = {v.x, v.y, v.z, v.w};
    unsigned short h[4], l[4];
#pragma unroll
    for (int q = 0; q < 4; ++q) {
      h[q] = f2bf_rne(f[q]);
      float hv = __uint_as_float(((unsigned)h[q]) << 16);
      l[q] = f2bf_rne(f[q] - hv);
    }
    int sw = (c4 * 8) ^ ((row & 7) << 4);
    unsigned short* Ht = half ? YH : XH;
    unsigned short* Lt = half ? YL : XL;
    *(ushort4*)((char*)Ht + row * 128 + sw) = make_ushort4(h[0], h[1], h[2], h[3]);
    *(ushort4*)((char*)Lt + row * 128 + sw) = make_ushort4(l[0], l[1], l[2], l[3]);
  }
  __syncthreads();
  const int lane = tid & 63;
  const int wid = tid >> 6;
  const int wr = wid >> 1, wc = wid & 1;
  const int lr = lane & 15;
  const int hg = lane >> 4;
  f32x4 acc[4][4];
#pragma unroll
  for (int a = 0; a < 4; ++a)
#pragma unroll
    for (int c = 0; c < 4; ++c) acc[a][c] = (f32x4){0.f, 0.f, 0.f, 0.f};
  const unsigned short* At[3] = {XH, XL, XH};
  const unsigned short* Bt[3] = {YH, YH, YL};
#pragma unroll
  for (int p = 0; p < 3; ++p) {
#pragma unroll
    for (int s = 0; s < 2; ++s) {
      const int kbyte = s * 64 + hg * 16;
      short8 af[4], bfv[4];
#pragma unroll
      for (int m2 = 0; m2 < 4; ++m2) {
        int row = wr * 64 + m2 * 16 + lr;
        af[m2] = *(const short8*)((const char*)At[p] + row * 128 + (kbyte ^ ((row & 7) << 4)));
      }
#pragma unroll
      for (int n2 = 0; n2 < 4; ++n2) {
        int row = wc * 64 + n2 * 16 + lr;
        bfv[n2] = *(const short8*)((const char*)Bt[p] + row * 128 + (kbyte ^ ((row & 7) << 4)));
      }
#pragma unroll
      for (int m2 = 0; m2 < 4; ++m2)
#pragma unroll
        for (int n2 = 0; n2 < 4; ++n2)
          acc[m2][n2] = __builtin_amdgcn_mfma_f32_16x16x32_bf16(af[m2], bfv[n2], acc[m2][n2], 0, 0, 0);
    }
  }
  const float g = *gptr;
  float yv[4];
#pragma unroll
  for (int n2 = 0; n2 < 4; ++n2) yv[n2] = ysq[j0 + wc * 64 + n2 * 16 + lr];
#pragma unroll
  for (int m2 = 0; m2 < 4; ++m2) {
#pragma unroll
    for (int j = 0; j < 4; ++j) {
      long row = i0 + wr * 64 + m2 * 16 + hg * 4 + j;
      float xr = xsq[row];
      float* op = Out + row * (long)mcols + j0 + wc * 64 + lr;
#pragma unroll
      for (int n2 = 0; n2 < 4; ++n2) {
        float d = fmaxf(xr + yv[n2] - 2.0f * acc[m2][n2][j], 0.f);
        op[n2 * 16] = __expf(-g * d);
      }
    }
  }
}

extern "C" void kernel_launch(void* const* d_in, const int* in_sizes, int n_in,
                              void* d_out, int out_size, void* d_ws, size_t ws_size,
                              hipStream_t stream) {
  const float* x = (const float*)d_in[0];
  const float* y = (const float*)d_in[1];
  const float* g = (const float*)d_in[2];
  float* out = (float*)d_out;

  const int n = in_sizes[0] / DD;   // 8192
  const int m = in_sizes[1] / DD;   // 8192

  const size_t split_bytes = (size_t)(n + m) * DD * 2 * sizeof(unsigned short);
  const size_t needed = split_bytes + (size_t)(n + m) * sizeof(float);

  if (ws_size >= needed && (n % BM) == 0 && (m % BN) == 0) {
    unsigned short* XHg = (unsigned short*)d_ws;
    unsigned short* XLg = XHg + (size_t)n * DD;
    unsigned short* YHg = XLg + (size_t)n * DD;
    unsigned short* YLg = YHg + (size_t)m * DD;
    float* xsq = (float*)(YLg + (size_t)m * DD);
    float* ysq = xsq + n;
    prep_split<<<(n + m) / 16, 256, 0, stream>>>(x, y, XHg, XLg, YHg, YLg, xsq, ysq, n);
    dim3 grid(m / BN, n / BM);      // 64 x 64 = 4096 blocks
    rbf_strip<<<grid, 256, 0, stream>>>(XHg, XLg, YHg, YLg, g, xsq, ysq, out, m);
  } else {
    float* xsq = (float*)d_ws;
    float* ysq = xsq + n;
    prep_sq<<<(n + m) / 16, 256, 0, stream>>>(x, y, xsq, ysq, n);
    dim3 grid2(m / 128, n / 128);
    rbf_mfma_fb<<<grid2, 256, 0, stream>>>(x, y, g, xsq, ysq, out, m);
  }
}

// Round 12
// 56.171 us; speedup vs baseline: 1.4505x; 1.0384x over previous
//
#include <hip/hip_runtime.h>
#include <hip/hip_bf16.h>

// RBF kernel matrix: out[i][j] = exp(-gamma * max(x2[i] + y2[j] - 2*x.y, 0))
//
// Round 12: r11 + ENFORCED fine-grained store interleave.
// r11 (strip-outer stores) gave the first real win (60.9 -> 58.3), but the
// unrolled strip loop let the scheduler re-cluster loads/stores. Now: hoist
// ALL A and B fragments to registers (128 VGPR), then 16 sub-tiles of 16x16,
// each = 6 reg-only MFMAs + 4 exp + ONE float4 store, fenced with
// sched_barrier(0) so stores stay evenly spaced through the wave lifetime.
// 3 MFMA passes (hi*hi + loY*hiX + hiY*loX), drop lo*lo (~1e-21 abs err).

#define DD 64
#define BM 128
#define BN 128

typedef __attribute__((ext_vector_type(8))) short short8;
typedef __attribute__((ext_vector_type(4))) float f32x4;

#if __has_builtin(__builtin_amdgcn_exp2f)
#define EXP2(x) __builtin_amdgcn_exp2f(x)
#else
#define EXP2(x) exp2f(x)
#endif

__device__ __forceinline__ unsigned short f2bf_rne(float f) {
  unsigned u = __float_as_uint(f);
  unsigned r = u + 0x7FFFu + ((u >> 16) & 1u);
  return (unsigned short)(r >> 16);
}

// ---------------- prep: fp32 norms + bf16 hi/lo pre-split (pre-swizzled) ----
__global__ __launch_bounds__(256)
void prep_split(const float* __restrict__ X, const float* __restrict__ Y,
                unsigned short* __restrict__ XHg, unsigned short* __restrict__ XLg,
                unsigned short* __restrict__ YHg, unsigned short* __restrict__ YLg,
                float* __restrict__ xsq, float* __restrict__ ysq, int n) {
  int t = blockIdx.x * 256 + threadIdx.x;
  int row = t >> 4;       // 16 lanes per row
  int c4 = t & 15;        // float4 index within row
  const float* src;
  unsigned short *hd, *ld;
  float* nd;
  int r;
  if (row < n) { r = row;     src = X + (long)r * DD; hd = XHg; ld = XLg; nd = xsq + r; }
  else         { r = row - n; src = Y + (long)r * DD; hd = YHg; ld = YLg; nd = ysq + r; }
  float4 v = ((const float4*)src)[c4];
  float f[4] = {v.x, v.y, v.z, v.w};
  unsigned short h[4], l[4];
#pragma unroll
  for (int q = 0; q < 4; ++q) {
    h[q] = f2bf_rne(f[q]);
    float hv = __uint_as_float(((unsigned)h[q]) << 16);
    l[q] = f2bf_rne(f[q] - hv);
  }
  int sw = (c4 * 8) ^ ((r & 7) << 4);   // swizzled byte offset within 128-B row
  *(ushort4*)((char*)hd + (long)r * 128 + sw) = make_ushort4(h[0], h[1], h[2], h[3]);
  *(ushort4*)((char*)ld + (long)r * 128 + sw) = make_ushort4(l[0], l[1], l[2], l[3]);
  float s = v.x * v.x + v.y * v.y + v.z * v.z + v.w * v.w;
  s += __shfl_xor(s, 1);
  s += __shfl_xor(s, 2);
  s += __shfl_xor(s, 4);
  s += __shfl_xor(s, 8);
  if (c4 == 0) *nd = s;
}

// ---------------- main: all-frags-in-reg, 16 fenced sub-tiles ---------------
__global__ __launch_bounds__(256, 2)
void rbf_fence(const unsigned short* __restrict__ XHg, const unsigned short* __restrict__ XLg,
               const unsigned short* __restrict__ YHg, const unsigned short* __restrict__ YLg,
               const float* __restrict__ gptr,
               const float* __restrict__ xsq, const float* __restrict__ ysq,
               float* __restrict__ Out, int mcols) {
  // 4 tiles of 128 rows x 128 B (swizzled image), 16 KB each = 64 KB.
  __shared__ __align__(128) char lds[65536];

  const int tid = threadIdx.x;
  const int lane = tid & 63;
  const int wid = tid >> 6;        // 0..3
  const long i0 = (long)blockIdx.y * BM;
  const long j0 = (long)blockIdx.x * BN;

  // ---- stage: 4 contiguous 16-KB slices, global_load_lds width 16
  const char* srcs[4] = {(const char*)XHg + i0 * 128, (const char*)XLg + i0 * 128,
                         (const char*)YHg + j0 * 128, (const char*)YLg + j0 * 128};
#pragma unroll
  for (int t4 = 0; t4 < 4; ++t4) {
#pragma unroll
    for (int it = 0; it < 4; ++it) {
      int off = it * 4096 + wid * 1024;           // wave-uniform
      const char* g = srcs[t4] + off + lane * 16; // per-lane global src
      __builtin_amdgcn_global_load_lds(
          (const __attribute__((address_space(1))) void*)g,
          (__attribute__((address_space(3))) void*)(lds + t4 * 16384 + off),
          16, 0, 0);
    }
  }
  __syncthreads();   // compiler drains vmcnt before the barrier

  const int wr = wid >> 1, wc = wid & 1;
  const int lr = lane & 15;
  const int hg = lane >> 4;        // 0..3

  // ---- hoist ALL fragments to registers (A: 64 VGPR, B: 64 VGPR)
  short8 afh[2][4], afl[2][4];     // [s][m2]
  short8 bfh[2][4], bfl[2][4];     // [s][n2]
#pragma unroll
  for (int s = 0; s < 2; ++s)
#pragma unroll
    for (int q = 0; q < 4; ++q) {
      int ra = wr * 64 + q * 16 + lr;
      int oa = (s * 64 + hg * 16) ^ ((ra & 7) << 4);
      afh[s][q] = *(const short8*)(lds + ra * 128 + oa);
      afl[s][q] = *(const short8*)(lds + 16384 + ra * 128 + oa);
      int rb = wc * 64 + q * 16 + lr;
      int ob = (s * 64 + hg * 16) ^ ((rb & 7) << 4);
      bfh[s][q] = *(const short8*)(lds + 32768 + rb * 128 + ob);
      bfl[s][q] = *(const short8*)(lds + 49152 + rb * 128 + ob);
    }

  const float g = *gptr;
  const float cf = -g * 1.4426950408889634f;   // -gamma*log2(e)
  const float nc2 = -2.0f * cf;
  float cxr[4];
#pragma unroll
  for (int m2 = 0; m2 < 4; ++m2) cxr[m2] = cf * xsq[i0 + wr * 64 + m2 * 16 + lr];
  float4 cyv[4];
#pragma unroll
  for (int n2 = 0; n2 < 4; ++n2) {
    float4 yq = *(const float4*)&ysq[j0 + wc * 64 + n2 * 16 + hg * 4];
    cyv[n2] = make_float4(cf * yq.x, cf * yq.y, cf * yq.z, cf * yq.w);
  }

  // ---- 16 sub-tiles: 6 MFMAs + 4 exp + 1 store each, order pinned
#pragma unroll
  for (int m2 = 0; m2 < 4; ++m2) {
    long row = i0 + wr * 64 + m2 * 16 + lr;
    float* op = Out + row * (long)mcols + j0 + wc * 64 + hg * 4;
#pragma unroll
    for (int n2 = 0; n2 < 4; ++n2) {
      f32x4 acc = (f32x4){0.f, 0.f, 0.f, 0.f};
#pragma unroll
      for (int s = 0; s < 2; ++s) {
        acc = __builtin_amdgcn_mfma_f32_16x16x32_bf16(bfh[s][n2], afh[s][m2], acc, 0, 0, 0);
        acc = __builtin_amdgcn_mfma_f32_16x16x32_bf16(bfh[s][n2], afl[s][m2], acc, 0, 0, 0);
        acc = __builtin_amdgcn_mfma_f32_16x16x32_bf16(bfl[s][n2], afh[s][m2], acc, 0, 0, 0);
      }
      float cy[4] = {cyv[n2].x, cyv[n2].y, cyv[n2].z, cyv[n2].w};
      float o[4];
#pragma unroll
      for (int j = 0; j < 4; ++j)
        o[j] = EXP2(fminf(fmaf(nc2, acc[j], cxr[m2] + cy[j]), 0.f));
      *(float4*)(op + n2 * 16) = *(float4*)o;
      __builtin_amdgcn_sched_barrier(0);   // pin: no cross-sub-tile re-clustering
    }
  }
}

// ---------------- fallback (proven round-2 path) ---------------------------
__global__ __launch_bounds__(256)
void prep_sq(const float* __restrict__ X, const float* __restrict__ Y,
             float* __restrict__ xsq, float* __restrict__ ysq, int n) {
  int t = blockIdx.x * 256 + threadIdx.x;
  int row = t >> 4;
  int c = t & 15;
  const float* src;
  float* dst;
  if (row < n) { src = X + (long)row * DD; dst = xsq + row; }
  else         { src = Y + (long)(row - n) * DD; dst = ysq + (row - n); }
  float4 v = ((const float4*)src)[c];
  float s = v.x * v.x + v.y * v.y + v.z * v.z + v.w * v.w;
  s += __shfl_xor(s, 1);
  s += __shfl_xor(s, 2);
  s += __shfl_xor(s, 4);
  s += __shfl_xor(s, 8);
  if (c == 0) *dst = s;
}

__global__ __launch_bounds__(256, 2)
void rbf_mfma_fb(const float* __restrict__ X, const float* __restrict__ Y,
                 const float* __restrict__ gptr,
                 const float* __restrict__ xsq, const float* __restrict__ ysq,
                 float* __restrict__ Out, int mcols) {
  __shared__ unsigned short XH[128 * DD], XL[128 * DD];
  __shared__ unsigned short YH[128 * DD], YL[128 * DD];
  const int tid = threadIdx.x;
  const long i0 = (long)blockIdx.y * 128;
  const long j0 = (long)blockIdx.x * 128;
#pragma unroll
  for (int it = 0; it < 16; ++it) {
    int e = it * 256 + tid;
    int half = e >> 11;
    int idx = e & 2047;
    int row = idx >> 4;
    int c4 = idx & 15;
    const float* src = half ? (Y + (j0 + row) * DD) : (X + (i0 + row) * DD);
    float4 v = ((const float4*)src)[c4];
    float f[4] = {v.x, v.y, v.z, v.w};
    unsigned short h[4], l[4];
#pragma unroll
    for (int q = 0; q < 4; ++q) {
      h[q] = f2bf_rne(f[q]);
      float hv = __uint_as_float(((unsigned)h[q]) << 16);
      l[q] = f2bf_rne(f[q] - hv);
    }
    int sw = (c4 * 8) ^ ((row & 7) << 4);
    unsigned short* Ht = half ? YH : XH;
    unsigned short* Lt = half ? YL : XL;
    *(ushort4*)((char*)Ht + row * 128 + sw) = make_ushort4(h[0], h[1], h[2], h[3]);
    *(ushort4*)((char*)Lt + row * 128 + sw) = make_ushort4(l[0], l[1], l[2], l[3]);
  }
  __syncthreads();
  const int lane = tid & 63;
  const int wid = tid >> 6;
  const int wr = wid >> 1, wc = wid & 1;
  const int lr = lane & 15;
  const int hg = lane >> 4;
  f32x4 acc[4][4];
#pragma unroll
  for (int a = 0; a < 4; ++a)
#pragma unroll
    for (int c = 0; c < 4; ++c) acc[a][c] = (f32x4){0.f, 0.f, 0.f, 0.f};
  const unsigned short* At[3] = {XH, XL, XH};
  const unsigned short* Bt[3] = {YH, YH, YL};
#pragma unroll
  for (int p = 0; p < 3; ++p) {
#pragma unroll
    for (int s = 0; s < 2; ++s) {
      const int kbyte = s * 64 + hg * 16;
      short8 af[4], bfv[4];
#pragma unroll
      for (int m2 = 0; m2 < 4; ++m2) {
        int row = wr * 64 + m2 * 16 + lr;
        af[m2] = *(const short8*)((const char*)At[p] + row * 128 + (kbyte ^ ((row & 7) << 4)));
      }
#pragma unroll
      for (int n2 = 0; n2 < 4; ++n2) {
        int row = wc * 64 + n2 * 16 + lr;
        bfv[n2] = *(const short8*)((const char*)Bt[p] + row * 128 + (kbyte ^ ((row & 7) << 4)));
      }
#pragma unroll
      for (int m2 = 0; m2 < 4; ++m2)
#pragma unroll
        for (int n2 = 0; n2 < 4; ++n2)
          acc[m2][n2] = __builtin_amdgcn_mfma_f32_16x16x32_bf16(af[m2], bfv[n2], acc[m2][n2], 0, 0, 0);
    }
  }
  const float g = *gptr;
  float yv[4];
#pragma unroll
  for (int n2 = 0; n2 < 4; ++n2) yv[n2] = ysq[j0 + wc * 64 + n2 * 16 + lr];
#pragma unroll
  for (int m2 = 0; m2 < 4; ++m2) {
#pragma unroll
    for (int j = 0; j < 4; ++j) {
      long row = i0 + wr * 64 + m2 * 16 + hg * 4 + j;
      float xr = xsq[row];
      float* op = Out + row * (long)mcols + j0 + wc * 64 + lr;
#pragma unroll
      for (int n2 = 0; n2 < 4; ++n2) {
        float d = fmaxf(xr + yv[n2] - 2.0f * acc[m2][n2][j], 0.f);
        op[n2 * 16] = __expf(-g * d);
      }
    }
  }
}

extern "C" void kernel_launch(void* const* d_in, const int* in_sizes, int n_in,
                              void* d_out, int out_size, void* d_ws, size_t ws_size,
                              hipStream_t stream) {
  const float* x = (const float*)d_in[0];
  const float* y = (const float*)d_in[1];
  const float* g = (const float*)d_in[2];
  float* out = (float*)d_out;

  const int n = in_sizes[0] / DD;   // 8192
  const int m = in_sizes[1] / DD;   // 8192

  const size_t split_bytes = (size_t)(n + m) * DD * 2 * sizeof(unsigned short);
  const size_t needed = split_bytes + (size_t)(n + m) * sizeof(float);

  if (ws_size >= needed && (n % BM) == 0 && (m % BN) == 0) {
    unsigned short* XHg = (unsigned short*)d_ws;
    unsigned short* XLg = XHg + (size_t)n * DD;
    unsigned short* YHg = XLg + (size_t)n * DD;
    unsigned short* YLg = YHg + (size_t)m * DD;
    float* xsq = (float*)(YLg + (size_t)m * DD);
    float* ysq = xsq + n;
    prep_split<<<(n + m) / 16, 256, 0, stream>>>(x, y, XHg, XLg, YHg, YLg, xsq, ysq, n);
    dim3 grid(m / BN, n / BM);      // 64 x 64 = 4096 blocks
    rbf_fence<<<grid, 256, 0, stream>>>(XHg, XLg, YHg, YLg, g, xsq, ysq, out, m);
  } else {
    float* xsq = (float*)d_ws;
    float* ysq = xsq + n;
    prep_sq<<<(n + m) / 16, 256, 0, stream>>>(x, y, xsq, ysq, n);
    dim3 grid2(m / 128, n / 128);
    rbf_mfma_fb<<<grid2, 256, 0, stream>>>(x, y, g, xsq, ysq, out, m);
  }
}